// Round 1
// baseline (5990.362 us; speedup 1.0000x reference)
//
#include <hip/hip_runtime.h>

// 2-layer LSTM (B=1024, T=256, I=14, H=128) + linear head (C=1).
// Baseline: fp32 VALU, persistent blocks over batch, weights streamed from L2.
// Each block: BB=4 batch rows, 256 threads (thread = 2 gate rows of 512),
// both layers fused in one time loop. 4 barriers/step.

#define BB        4
#define NTHREADS  256
#define T_STEPS   256
#define I_DIM     14
#define H_DIM     128
#define G4        512

__device__ __forceinline__ float sig_(float z)  { return 1.f / (1.f + __expf(-z)); }
__device__ __forceinline__ float tanh_(float z) { return 1.f - 2.f / (1.f + __expf(2.f * z)); }

__global__ __launch_bounds__(NTHREADS) void lstm2_fused(
    const float* __restrict__ x,
    const float* __restrict__ w_ih0, const float* __restrict__ w_hh0,
    const float* __restrict__ b_ih0, const float* __restrict__ b_hh0,
    const float* __restrict__ w_ih1, const float* __restrict__ w_hh1,
    const float* __restrict__ b_ih1, const float* __restrict__ b_hh1,
    const float* __restrict__ w_lin, const float* __restrict__ b_lin,
    float* __restrict__ out)
{
    __shared__ float h1[H_DIM][BB];     // transposed [k][b] so one float4 = 4 rows
    __shared__ float h2[H_DIM][BB];
    __shared__ float zbuf[BB][G4];      // gate pre-activations
    __shared__ float xbuf[BB][16];      // current x rows (14 used)

    const int tid = threadIdx.x;
    const int b0  = blockIdx.x * BB;
    const int g0  = tid;                // gate row a
    const int g1  = tid + 256;          // gate row b

    // zero hidden state
    for (int i = tid; i < H_DIM * BB; i += NTHREADS) {
        (&h1[0][0])[i] = 0.f;
        (&h2[0][0])[i] = 0.f;
    }

    // layer-1 input-projection weights: per-thread registers (I=14)
    float wx0[I_DIM], wx1[I_DIM];
#pragma unroll
    for (int k = 0; k < I_DIM; ++k) {
        wx0[k] = w_ih0[g0 * I_DIM + k];
        wx1[k] = w_ih0[g1 * I_DIM + k];
    }
    const float bias1a = b_ih0[g0] + b_hh0[g0];
    const float bias1b = b_ih0[g1] + b_hh0[g1];
    const float bias2a = b_ih1[g0] + b_hh1[g0];
    const float bias2b = b_ih1[g1] + b_hh1[g1];

    // activation-role mapping: thread -> units (ab0, aj) and (ab1, aj)
    const int aj  = tid & 127;
    const int ab0 = tid >> 7;       // 0 or 1
    const int ab1 = ab0 + 2;        // 2 or 3
    float c1a = 0.f, c1b = 0.f, c2a = 0.f, c2b = 0.f;

    const float* wr_hh0_a = w_hh0 + g0 * H_DIM;
    const float* wr_hh0_b = w_hh0 + g1 * H_DIM;
    const float* wr_ih1_a = w_ih1 + g0 * H_DIM;
    const float* wr_ih1_b = w_ih1 + g1 * H_DIM;
    const float* wr_hh1_a = w_hh1 + g0 * H_DIM;
    const float* wr_hh1_b = w_hh1 + g1 * H_DIM;

    __syncthreads();

    float za[BB], zb[BB];

#define MATMUL_ACC(WPTR_A, WPTR_B, HBUF)                                          \
    {                                                                             \
        _Pragma("unroll 8")                                                       \
        for (int k = 0; k < H_DIM; k += 4) {                                      \
            const float4 wa = *(const float4*)((WPTR_A) + k);                     \
            const float4 wb = *(const float4*)((WPTR_B) + k);                     \
            _Pragma("unroll")                                                     \
            for (int u = 0; u < 4; ++u) {                                         \
                const float w_a = ((const float*)&wa)[u];                         \
                const float w_b = ((const float*)&wb)[u];                         \
                const float4 hv = *(const float4*)(&(HBUF)[k + u][0]);            \
                za[0] += w_a * hv.x; za[1] += w_a * hv.y;                         \
                za[2] += w_a * hv.z; za[3] += w_a * hv.w;                         \
                zb[0] += w_b * hv.x; zb[1] += w_b * hv.y;                         \
                zb[2] += w_b * hv.z; zb[3] += w_b * hv.w;                         \
            }                                                                     \
        }                                                                         \
    }

    for (int t = 0; t < T_STEPS; ++t) {
        // (A) stage x rows for this step
        if (tid < BB * I_DIM) {
            const int b = tid / I_DIM, i = tid - b * I_DIM;
            xbuf[b][i] = x[(size_t)(b0 + b) * (T_STEPS * I_DIM) + t * I_DIM + i];
        }
        __syncthreads();   // barrier 1

        // (B) layer-1 gate pre-activations
#pragma unroll
        for (int b = 0; b < BB; ++b) { za[b] = bias1a; zb[b] = bias1b; }
#pragma unroll
        for (int k = 0; k < I_DIM; ++k) {
            const float w_a = wx0[k], w_b = wx1[k];
#pragma unroll
            for (int b = 0; b < BB; ++b) {
                const float xv = xbuf[b][k];
                za[b] += w_a * xv;
                zb[b] += w_b * xv;
            }
        }
        MATMUL_ACC(wr_hh0_a, wr_hh0_b, h1);
#pragma unroll
        for (int b = 0; b < BB; ++b) { zbuf[b][g0] = za[b]; zbuf[b][g1] = zb[b]; }
        __syncthreads();   // barrier 2

        // (C) layer-1 activations: c1,h1 update
        {
            float zi = zbuf[ab0][aj], zf = zbuf[ab0][aj + 128];
            float zg = zbuf[ab0][aj + 256], zo = zbuf[ab0][aj + 384];
            float ig = sig_(zi), fg = sig_(zf), gv = tanh_(zg), og = sig_(zo);
            c1a = fg * c1a + ig * gv;
            h1[aj][ab0] = og * tanh_(c1a);
            zi = zbuf[ab1][aj]; zf = zbuf[ab1][aj + 128];
            zg = zbuf[ab1][aj + 256]; zo = zbuf[ab1][aj + 384];
            ig = sig_(zi); fg = sig_(zf); gv = tanh_(zg); og = sig_(zo);
            c1b = fg * c1b + ig * gv;
            h1[aj][ab1] = og * tanh_(c1b);
        }
        __syncthreads();   // barrier 3

        // (D) layer-2 gate pre-activations (uses fresh h1, old h2)
#pragma unroll
        for (int b = 0; b < BB; ++b) { za[b] = bias2a; zb[b] = bias2b; }
        MATMUL_ACC(wr_ih1_a, wr_ih1_b, h1);
        MATMUL_ACC(wr_hh1_a, wr_hh1_b, h2);
#pragma unroll
        for (int b = 0; b < BB; ++b) { zbuf[b][g0] = za[b]; zbuf[b][g1] = zb[b]; }
        __syncthreads();   // barrier 4

        // (E) layer-2 activations: c2,h2 update
        {
            float zi = zbuf[ab0][aj], zf = zbuf[ab0][aj + 128];
            float zg = zbuf[ab0][aj + 256], zo = zbuf[ab0][aj + 384];
            float ig = sig_(zi), fg = sig_(zf), gv = tanh_(zg), og = sig_(zo);
            c2a = fg * c2a + ig * gv;
            h2[aj][ab0] = og * tanh_(c2a);
            zi = zbuf[ab1][aj]; zf = zbuf[ab1][aj + 128];
            zg = zbuf[ab1][aj + 256]; zo = zbuf[ab1][aj + 384];
            ig = sig_(zi); fg = sig_(zf); gv = tanh_(zg); og = sig_(zo);
            c2b = fg * c2b + ig * gv;
            h2[aj][ab1] = og * tanh_(c2b);
        }
        // next iteration's barrier 1 orders (E) against next (B)/(D)
    }

    __syncthreads();
    // epilogue: out[b] = h2_last[b] . w_lin + b_lin
    if (tid < BB) {
        float acc = b_lin[0];
#pragma unroll 8
        for (int j = 0; j < H_DIM; ++j) acc += w_lin[j] * h2[j][tid];
        out[b0 + tid] = acc;
    }
#undef MATMUL_ACC
}

extern "C" void kernel_launch(void* const* d_in, const int* in_sizes, int n_in,
                              void* d_out, int out_size, void* d_ws, size_t ws_size,
                              hipStream_t stream) {
    (void)in_sizes; (void)n_in; (void)d_ws; (void)ws_size; (void)out_size;
    const float* x     = (const float*)d_in[0];
    const float* w_ih0 = (const float*)d_in[1];
    const float* w_hh0 = (const float*)d_in[2];
    const float* b_ih0 = (const float*)d_in[3];
    const float* b_hh0 = (const float*)d_in[4];
    const float* w_ih1 = (const float*)d_in[5];
    const float* w_hh1 = (const float*)d_in[6];
    const float* b_ih1 = (const float*)d_in[7];
    const float* b_hh1 = (const float*)d_in[8];
    const float* w_lin = (const float*)d_in[9];
    const float* b_lin = (const float*)d_in[10];
    float* out = (float*)d_out;

    dim3 grid(1024 / BB), block(NTHREADS);
    hipLaunchKernelGGL(lstm2_fused, grid, block, 0, stream,
                       x, w_ih0, w_hh0, b_ih0, b_hh0,
                       w_ih1, w_hh1, b_ih1, b_hh1, w_lin, b_lin, out);
}

// Round 2
// 515.898 us; speedup vs baseline: 11.6115x; 11.6115x over previous
//
#include <hip/hip_runtime.h>

typedef _Float16 half8 __attribute__((ext_vector_type(8)));
typedef float floatx4 __attribute__((ext_vector_type(4)));

#define T_STEPS 256
#define BB      16      // batch rows per block
#define NBLK    64      // 1024/BB
#define NTH     512     // 8 waves

// ws layout in halves: whh0 frags | wih1 frags | whh1 frags | wih0 frags
#define WHH0_H  0
#define WIH1_H  65536
#define WHH1_H  131072
#define WIH0_H  196608

__device__ __forceinline__ float sig_(float z)  { return __builtin_amdgcn_rcpf(1.f + __expf(-z)); }
__device__ __forceinline__ float tanh_(float z) { return 1.f - 2.f * __builtin_amdgcn_rcpf(1.f + __expf(2.f * z)); }

// Build fp16 MFMA B-fragment arrays.
// Frag index: ((wv*4+gi)*4+ks)*64 + lane ; lane holds W[gi*128+wv*16+(l&15)][ks*32+(l>>4)*8 + j], j=0..7
__global__ __launch_bounds__(256) void prep_weights(
    const float* __restrict__ w_ih0, const float* __restrict__ w_hh0,
    const float* __restrict__ w_ih1, const float* __restrict__ w_hh1,
    _Float16* __restrict__ wf)
{
    const int idx = blockIdx.x * 256 + threadIdx.x;   // 0..8191
    const int l  = idx & 63;
    const int ks = (idx >> 6) & 3;
    const int gi = (idx >> 8) & 3;
    const int wv = (idx >> 10) & 7;
    const int row = gi * 128 + wv * 16 + (l & 15);
    const int kb  = ks * 32 + (l >> 4) * 8;
#pragma unroll
    for (int j = 0; j < 8; ++j) {
        wf[WHH0_H + idx * 8 + j] = (_Float16)w_hh0[row * 128 + kb + j];
        wf[WIH1_H + idx * 8 + j] = (_Float16)w_ih1[row * 128 + kb + j];
        wf[WHH1_H + idx * 8 + j] = (_Float16)w_hh1[row * 128 + kb + j];
    }
    if (ks == 0) {   // x-projection weights: K=14 zero-padded to 32 (one k-step)
        const int kb0 = (l >> 4) * 8;
        const int oi = ((wv * 4 + gi) * 64 + l) * 8;
#pragma unroll
        for (int j = 0; j < 8; ++j) {
            const int k = kb0 + j;
            wf[WIH0_H + oi + j] = (k < 14) ? (_Float16)w_ih0[row * 14 + k] : (_Float16)0.f;
        }
    }
}

__global__ __launch_bounds__(NTH) void lstm2_mfma(
    const float* __restrict__ x, const _Float16* __restrict__ wf,
    const float* __restrict__ b_ih0, const float* __restrict__ b_hh0,
    const float* __restrict__ b_ih1, const float* __restrict__ b_hh1,
    const float* __restrict__ w_lin, const float* __restrict__ b_lin,
    float* __restrict__ out)
{
    __shared__ __align__(16) _Float16 whh0_lds[65536];       // 128 KB, frag-ordered
    __shared__ __align__(16) _Float16 h1buf[2][BB][128];     // 8 KB, XOR-swizzled
    __shared__ __align__(16) _Float16 h2buf[2][BB][128];     // 8 KB
    __shared__ __align__(16) _Float16 xlds[2][BB][32];       // 2 KB, cols >=14 zero

    const int tid  = threadIdx.x;
    const int l    = tid & 63;
    const int wv   = tid >> 6;
    const int lrow = l & 15;      // A-row / B-col / D-col
    const int lk   = l >> 4;      // k-group
    const int b0   = blockIdx.x * BB;

    // ---- init: stage whh0 frags to LDS ----
    {
        const floatx4* src = (const floatx4*)(wf + WHH0_H);
        floatx4* dst = (floatx4*)whh0_lds;
        for (int i = tid; i < 8192; i += NTH) dst[i] = src[i];
    }
    // zero h(-1) buffers and all of xlds (incl. pad cols)
    for (int i = tid; i < 1024; i += NTH) {
        ((unsigned*)h1buf[1])[i] = 0u;
        ((unsigned*)h2buf[1])[i] = 0u;
    }
    for (int i = tid; i < 512; i += NTH) ((unsigned*)xlds)[i] = 0u;

    // x loader role: 224 threads, one value each per step
    const int xr = tid / 14, xc = tid - xr * 14;
    const bool xload = tid < 224;
    const float* xptr = xload ? (x + (size_t)(b0 + xr) * (T_STEPS * 14) + xc) : x;
    if (xload) xlds[0][xr][xc] = (_Float16)xptr[0];   // stage x(0)

    // register-resident weight fragments (static indexing only)
    half8 wih1f[16], whh1f[16], wih0f[4];
    {
        const half8* wsf = (const half8*)wf;
#pragma unroll
        for (int gi = 0; gi < 4; ++gi) {
#pragma unroll
            for (int ks = 0; ks < 4; ++ks) {
                const int idx = ((wv * 4 + gi) * 4 + ks) * 64 + l;
                wih1f[gi * 4 + ks] = wsf[WIH1_H / 8 + idx];
                whh1f[gi * 4 + ks] = wsf[WHH1_H / 8 + idx];
            }
            wih0f[gi] = wsf[WIH0_H / 8 + (wv * 4 + gi) * 64 + l];
        }
    }

    float bias1[4], bias2[4];
#pragma unroll
    for (int gi = 0; gi < 4; ++gi) {
        const int col = gi * 128 + wv * 16 + lrow;
        bias1[gi] = b_ih0[col] + b_hh0[col];
        bias2[gi] = b_ih1[col] + b_hh1[col];
    }

    float c1[4] = {0.f, 0.f, 0.f, 0.f}, c2[4] = {0.f, 0.f, 0.f, 0.f};

    const int fragcol = lk * 16;   // byte offset of this lane's k-chunk within a row
    const char* wbase = (const char*)whh0_lds + ((wv * 16) * 64 + l) * 16;

    __syncthreads();

#pragma unroll 2
    for (int t = 0; t < T_STEPS; ++t) {
        const int cur = t & 1, prv = cur ^ 1;

        // issue next-step x load early (hidden under this step's MFMA)
        float xnext = 0.f;
        if (xload && t < T_STEPS - 1) xnext = xptr[(t + 1) * 14];

        // A-frags of h1(t-1), h2(t-1)  (XOR-swizzled ds_read_b128)
        const char* h1rd = (const char*)h1buf[prv];
        const char* h2rd = (const char*)h2buf[prv];
        half8 h1p[4], h2p[4];
#pragma unroll
        for (int ks = 0; ks < 4; ++ks) {
            const int off = lrow * 256 + ((ks * 64 + fragcol) ^ ((lrow & 7) << 4));
            h1p[ks] = *(const half8*)(h1rd + off);
            h2p[ks] = *(const half8*)(h2rd + off);
        }
        half8 xa = *(const half8*)((const char*)xlds[cur] + lrow * 64 + fragcol);

        // layer-1 gates: x-proj + h1(t-1) @ whh0 (LDS frags)
        floatx4 acc1[4], acc2[4];
#pragma unroll
        for (int gi = 0; gi < 4; ++gi) {
            acc1[gi] = (floatx4){bias1[gi], bias1[gi], bias1[gi], bias1[gi]};
            acc1[gi] = __builtin_amdgcn_mfma_f32_16x16x32_f16(xa, wih0f[gi], acc1[gi], 0, 0, 0);
#pragma unroll
            for (int ks = 0; ks < 4; ++ks) {
                const half8 wb = *(const half8*)(wbase + (gi * 4 + ks) * 1024);
                acc1[gi] = __builtin_amdgcn_mfma_f32_16x16x32_f16(h1p[ks], wb, acc1[gi], 0, 0, 0);
            }
        }
        // layer-2 hh part (independent of layer-1 acts -> overlaps them)
#pragma unroll
        for (int gi = 0; gi < 4; ++gi) {
            acc2[gi] = (floatx4){bias2[gi], bias2[gi], bias2[gi], bias2[gi]};
#pragma unroll
            for (int ks = 0; ks < 4; ++ks)
                acc2[gi] = __builtin_amdgcn_mfma_f32_16x16x32_f16(h2p[ks], whh1f[gi * 4 + ks], acc2[gi], 0, 0, 0);
        }

        // layer-1 activations + h1(t) write (lane owns unit j=wv*16+lrow, 4 batches)
        {
            char* h1wr = (char*)h1buf[cur];
#pragma unroll
            for (int r = 0; r < 4; ++r) {
                const float ig = sig_(acc1[0][r]);
                const float fg = sig_(acc1[1][r]);
                const float gg = tanh_(acc1[2][r]);
                const float og = sig_(acc1[3][r]);
                c1[r] = fg * c1[r] + ig * gg;
                const float hv = og * tanh_(c1[r]);
                const int b = lk * 4 + r;
                const int off = b * 256 + (((wv * 16 + lrow) * 2) ^ ((b & 7) << 4));
                *(_Float16*)(h1wr + off) = (_Float16)hv;
            }
        }

        __syncthreads();   // h1(t) visible

        // layer-2 ih part: h1(t) @ wih1 (register frags)
        {
            const char* h1nrd = (const char*)h1buf[cur];
#pragma unroll
            for (int ks = 0; ks < 4; ++ks) {
                const int off = lrow * 256 + ((ks * 64 + fragcol) ^ ((lrow & 7) << 4));
                const half8 h1n = *(const half8*)(h1nrd + off);
#pragma unroll
                for (int gi = 0; gi < 4; ++gi)
                    acc2[gi] = __builtin_amdgcn_mfma_f32_16x16x32_f16(h1n, wih1f[gi * 4 + ks], acc2[gi], 0, 0, 0);
            }
        }

        // layer-2 activations + h2(t) write
        {
            char* h2wr = (char*)h2buf[cur];
#pragma unroll
            for (int r = 0; r < 4; ++r) {
                const float ig = sig_(acc2[0][r]);
                const float fg = sig_(acc2[1][r]);
                const float gg = tanh_(acc2[2][r]);
                const float og = sig_(acc2[3][r]);
                c2[r] = fg * c2[r] + ig * gg;
                const float hv = og * tanh_(c2[r]);
                const int b = lk * 4 + r;
                const int off = b * 256 + (((wv * 16 + lrow) * 2) ^ ((b & 7) << 4));
                *(_Float16*)(h2wr + off) = (_Float16)hv;
            }
        }

        // stage x(t+1) into the buffer read next step
        if (xload && t < T_STEPS - 1) xlds[prv][xr][xc] = (_Float16)xnext;

        __syncthreads();   // h2(t) + x(t+1) visible
    }

    // epilogue: out[b] = h2(255)[b] . w_lin + b_lin ; h2(255) is in h2buf[1]
    if (tid < BB) {
        const char* hb = (const char*)h2buf[1];
        float acc = b_lin[0];
        for (int j = 0; j < 128; ++j) {
            const int off = tid * 256 + ((j * 2) ^ ((tid & 7) << 4));
            acc += w_lin[j] * (float)(*(const _Float16*)(hb + off));
        }
        out[b0 + tid] = acc;
    }
}

extern "C" void kernel_launch(void* const* d_in, const int* in_sizes, int n_in,
                              void* d_out, int out_size, void* d_ws, size_t ws_size,
                              hipStream_t stream) {
    (void)in_sizes; (void)n_in; (void)ws_size; (void)out_size;
    const float* x     = (const float*)d_in[0];
    const float* w_ih0 = (const float*)d_in[1];
    const float* w_hh0 = (const float*)d_in[2];
    const float* b_ih0 = (const float*)d_in[3];
    const float* b_hh0 = (const float*)d_in[4];
    const float* w_ih1 = (const float*)d_in[5];
    const float* w_hh1 = (const float*)d_in[6];
    const float* b_ih1 = (const float*)d_in[7];
    const float* b_hh1 = (const float*)d_in[8];
    const float* w_lin = (const float*)d_in[9];
    const float* b_lin = (const float*)d_in[10];
    float* out = (float*)d_out;
    _Float16* wf = (_Float16*)d_ws;

    hipLaunchKernelGGL(prep_weights, dim3(32), dim3(256), 0, stream,
                       w_ih0, w_hh0, w_ih1, w_hh1, wf);
    hipLaunchKernelGGL(lstm2_mfma, dim3(NBLK), dim3(NTH), 0, stream,
                       x, wf, b_ih0, b_hh0, b_ih1, b_hh1, w_lin, b_lin, out);
}